// Round 7
// baseline (617.572 us; speedup 1.0000x reference)
//
#include <hip/hip_runtime.h>
#include <hip/hip_bf16.h>

#define HDIM 128
#define NREL 16
#define NBASES 8
#define KSLOTS 17            // 16 relations + self-loop (weights only; AGG stores 16)
#define KDIM (KSLOTS * HDIM) // 2176

typedef short bf16x8 __attribute__((ext_vector_type(8)));
typedef short s16x4 __attribute__((ext_vector_type(4)));
typedef float f32x4 __attribute__((ext_vector_type(4)));

static __device__ __forceinline__ short f2bf(float x) {
    __hip_bfloat16 b = __float2bfloat16(x);
    return *(short*)&b;
}
static __device__ __forceinline__ float bf2f(short u) {
    unsigned v = ((unsigned)(unsigned short)u) << 16;
    return __uint_as_float(v);
}

// ---------------- weight prep ----------------
// wtL[o][r*128+i] = W_r[i][o] = sum_b wcomp[r][b]*basis[b][i][o]   (bf16)
__global__ void compute_wt(const float* __restrict__ basis,
                           const float* __restrict__ wcomp,
                           short* __restrict__ wtL) {
    int ro = blockIdx.x;
    int r = ro >> 7, o = ro & 127;
    int i = threadIdx.x;
    float acc = 0.f;
#pragma unroll
    for (int b = 0; b < NBASES; ++b)
        acc += wcomp[r * NBASES + b] * basis[(b * HDIM + i) * HDIM + o];
    wtL[(size_t)o * KDIM + r * HDIM + i] = f2bf(acc);
}

// wtL[o][2048+i] = loop_w[i][o]
__global__ void transposeL(const float* __restrict__ in, short* __restrict__ wtL) {
    int o = blockIdx.x, i = threadIdx.x;
    wtL[(size_t)o * KDIM + NREL * HDIM + i] = f2bf(in[i * HDIM + o]);
}

// fp32 -> bf16 cast (vectorized)
__global__ void cast_bf16(const float* __restrict__ in, short* __restrict__ out, int n4) {
    for (int i = blockIdx.x * blockDim.x + threadIdx.x; i < n4; i += gridDim.x * blockDim.x) {
        f32x4 v = ((const f32x4*)in)[i];
        s16x4 o;
#pragma unroll
        for (int j = 0; j < 4; ++j) o[j] = f2bf(v[j]);
        ((s16x4*)out)[i] = o;
    }
}

__global__ void zero_i32(int* __restrict__ p, int n) {
    int i = blockIdx.x * blockDim.x + threadIdx.x;
    if (i < n) p[i] = 0;
}

// ---------------- counting sort by key = dst*16 + rel (800K bins) ----------------
__global__ __launch_bounds__(256) void hist_k(const int* __restrict__ dst,
                                              const int* __restrict__ rel, int n,
                                              int* __restrict__ hist) {
    for (int i = blockIdx.x * blockDim.x + threadIdx.x; i < n; i += gridDim.x * blockDim.x)
        atomicAdd(&hist[dst[i] * NREL + rel[i]], 1);
}

__global__ __launch_bounds__(1024) void scan_p1(const int* __restrict__ hist, int n,
                                                int* __restrict__ off, int* __restrict__ part) {
    __shared__ int sh[1024];
    int t = threadIdx.x, b = blockIdx.x;
    int i = b * 1024 + t;
    int x = (i < n) ? hist[i] : 0;
    sh[t] = x;
    __syncthreads();
    for (int d = 1; d < 1024; d <<= 1) {
        int v = sh[t];
        int u = (t >= d) ? sh[t - d] : 0;
        __syncthreads();
        sh[t] = v + u;
        __syncthreads();
    }
    if (i < n) off[i] = sh[t] - x;
    if (t == 1023) part[b] = sh[t];
}

__global__ __launch_bounds__(1024) void scan_p2(int* __restrict__ part, int nb) {
    __shared__ int sh[1024];
    int t = threadIdx.x;
    int x = (t < nb) ? part[t] : 0;
    sh[t] = x;
    __syncthreads();
    for (int d = 1; d < 1024; d <<= 1) {
        int v = sh[t];
        int u = (t >= d) ? sh[t - d] : 0;
        __syncthreads();
        sh[t] = v + u;
        __syncthreads();
    }
    if (t < nb) part[t] = sh[t] - x;
}

__global__ __launch_bounds__(1024) void scan_p3(int* __restrict__ off, const int* __restrict__ part,
                                                int n, int nk, int* __restrict__ cur) {
    int i = blockIdx.x * 1024 + threadIdx.x;
    if (i < n) {
        int v = off[i] + part[blockIdx.x];
        off[i] = v;
        if (i < nk) cur[i] = v;
    }
}

// place edges: edge2[p] = src | rel<<16  (n_ent < 65536)
__global__ __launch_bounds__(256) void scatter_k(const int* __restrict__ src,
                                                 const int* __restrict__ dst,
                                                 const int* __restrict__ rel, int n,
                                                 int* __restrict__ cur,
                                                 int* __restrict__ edge2) {
    for (int i = blockIdx.x * blockDim.x + threadIdx.x; i < n; i += gridDim.x * blockDim.x) {
        int k = dst[i] * NREL + rel[i];
        int p = atomicAdd(&cur[k], 1);
        edge2[p] = (src[i] & 0xFFFF) | (rel[i] << 16);
    }
}

// ---------------- AGG build: barrier-free streaming gather ----------------
// Group = 16 lanes per (dst row, 8-slot rel-half). Edges of the 8 slots are
// contiguous in key-sorted edge2. Per slot classification (u16 srcs code):
//   0xFFFF = empty; 0xFFFE = multi-edge (aggregate written to AGG);
//   else   = the single edge's src id (NO gather, NO AGG write: gemm reads h).
__global__ __launch_bounds__(256) void agg_build(
    const short* __restrict__ h,
    const int* __restrict__ off,      // [NK+1], key-sorted offsets
    const int* __restrict__ edge2,    // src | rel<<16
    short* __restrict__ AGG,          // [rows][16][128] bf16 (valid where srcs==0xFFFE)
    unsigned short* __restrict__ srcs,// [rows][16] slot codes
    int c0, int rows) {
    int tid = threadIdx.x;
    int grp = blockIdx.x * 16 + (tid >> 4);
    int lane16 = tid & 15;
    int lane = tid & 63;
    int gb = lane & 48;               // 16-lane group base within wave
    int drow = grp >> 1;
    if (drow >= rows) return;
    int rh = (grp & 1) * 8;
    int d = c0 + drow;
    int kbase = d * NREL + rh;

    int e0 = off[kbase];
    int e8 = off[kbase + 8];
    int deg = e8 - e0;

    int pkv = (e0 + lane16 < e8) ? edge2[e0 + lane16] : 0;

    int rlv[17], srcv[16];
#pragma unroll
    for (int p = 0; p < 16; ++p) {
        int pk = __shfl(pkv, gb + p);
        rlv[p] = (p < deg) ? (((pk >> 16) & 15) - rh) : 255;
        srcv[p] = pk & 0xFFFF;
    }
    // forbid "single" at the window edge when a tail exists
    rlv[16] = (deg > 16) ? rlv[15] : 255;

    bool single[16];
#pragma unroll
    for (int p = 0; p < 16; ++p)
        single[p] = ((p == 0) || (rlv[p - 1] != rlv[p])) && (rlv[p + 1] != rlv[p]);

    // gather only multi-slot edges
    bf16x8 va[16];
#pragma unroll
    for (int p = 0; p < 16; ++p)
        if (p < deg && !single[p])
            va[p] = *(const bf16x8*)(h + (size_t)srcv[p] * HDIM + lane16 * 8);

    // slot code: lane l (<8) owns slot l of this half
    unsigned short val = 0xFFFF;
#pragma unroll
    for (int p = 0; p < 16; ++p)
        if (p < deg && rlv[p] == lane16)
            val = single[p] ? (unsigned short)srcv[p] : (unsigned short)0xFFFE;

    float acc[8] = {0.f, 0.f, 0.f, 0.f, 0.f, 0.f, 0.f, 0.f};
    int cs = -1;
    short* outp = AGG + ((size_t)drow * NREL + rh) * HDIM + lane16 * 8;

    auto emit = [&]() {
        bf16x8 o;
#pragma unroll
        for (int c = 0; c < 8; ++c) o[c] = f2bf(acc[c]);
        *(bf16x8*)(outp + cs * HDIM) = o;
    };
    auto take = [&](int sl, bf16x8 v) {
        if (sl != cs) {
            if (cs >= 0) emit();
            cs = sl;
#pragma unroll
            for (int c = 0; c < 8; ++c) acc[c] = 0.f;
        }
#pragma unroll
        for (int c = 0; c < 8; ++c) acc[c] += bf2f(v[c]);
    };

#pragma unroll
    for (int p = 0; p < 16; ++p)
        if (p < deg && !single[p]) take(rlv[p], va[p]);

    // rare tail: deg > 16 (Poisson(8) upper tail, ~0.4% of groups)
    for (int e = e0 + 16; e < e8; ++e) {
        int pk = edge2[e];
        int sl = ((pk >> 16) & 15) - rh;
        if (sl == lane16) val = 0xFFFE;
        bf16x8 v = *(const bf16x8*)(h + (size_t)(pk & 0xFFFF) * HDIM + lane16 * 8);
        take(sl, v);
    }
    if (cs >= 0) emit();

    if (lane16 < 8) srcs[(size_t)drow * NREL + rh + lane16] = val;
}

// ---------------- dense GEMM, all-register: out = relu([AGG|h] @ WstackT + b) ----------------
// Block = 64 rows x 128 cols, 256 threads (4 waves, wave-tile 32x64).
// NO LDS, NO barriers: every wave reads its A fragments straight from the
// indirected source (zero / h[src] / AGG row, per slot code) and its B
// fragments straight from L2-hot wtL. The 17-slot loop is fully unrolled
// (static slot-code indexing; rule #20) so loads of slot k+1 float under
// the MFMAs of slot k. Occupancy is VGPR-bound only.
__global__ __launch_bounds__(256, 2) void agg_gemm(
    const short* __restrict__ AGG,    // [rows][16][128] bf16
    const short* __restrict__ h,      // bf16 [N][128]
    const short* __restrict__ wtL,    // [128 o][2176 k] bf16
    const unsigned short* __restrict__ srcs, // [rows][16]
    const float* __restrict__ bias,   // [128]
    short* __restrict__ out_bf,       // layer-1 output (bf16) or nullptr
    float* __restrict__ out_f,        // layer-2 output (fp32) or nullptr
    int c0, int rows) {
    int tid = threadIdx.x;
    int row0 = blockIdx.x * 64;
    int wave = tid >> 6, lane = tid & 63;
    int mq = (wave & 1) * 32, nq = (wave >> 1) * 64;
    int lr = lane & 15, quad = lane >> 4;

    // the two A-rows this lane covers (mi = 0, 1)
    int ra = row0 + mq + lr;
    int rb = row0 + mq + 16 + lr;
    bool oka = ra < rows, okb = rb < rows;

    // slot codes for both rows (16 u16 each = 2 uint4)
    unsigned cA[8], cB[8];
    {
        uint4 ff = make_uint4(0xFFFFFFFFu, 0xFFFFFFFFu, 0xFFFFFFFFu, 0xFFFFFFFFu);
        uint4 a0 = ff, a1 = ff, b0 = ff, b1 = ff;
        if (oka) {
            const uint4* p = (const uint4*)(srcs + (size_t)ra * NREL);
            a0 = p[0]; a1 = p[1];
        }
        if (okb) {
            const uint4* p = (const uint4*)(srcs + (size_t)rb * NREL);
            b0 = p[0]; b1 = p[1];
        }
        cA[0] = a0.x; cA[1] = a0.y; cA[2] = a0.z; cA[3] = a0.w;
        cA[4] = a1.x; cA[5] = a1.y; cA[6] = a1.z; cA[7] = a1.w;
        cB[0] = b0.x; cB[1] = b0.y; cB[2] = b0.z; cB[3] = b0.w;
        cB[4] = b1.x; cB[5] = b1.y; cB[6] = b1.z; cB[7] = b1.w;
    }

    f32x4 acc[2][4] = {};
    const short* wbase = wtL + (size_t)(nq + lr) * KDIM;  // +ni*16*KDIM per ni

#pragma unroll
    for (int ks = 0; ks < KSLOTS; ++ks) {
        // resolve the two A-row source pointers for this slot
        const short* pa;
        const short* pb;
        if (ks == 16) {
            pa = oka ? h + (size_t)(c0 + ra) * HDIM : nullptr;
            pb = okb ? h + (size_t)(c0 + rb) * HDIM : nullptr;
        } else {
            unsigned ea = (cA[ks >> 1] >> ((ks & 1) * 16)) & 0xFFFFu;
            unsigned eb = (cB[ks >> 1] >> ((ks & 1) * 16)) & 0xFFFFu;
            pa = (ea == 0xFFFFu) ? nullptr
               : (ea == 0xFFFEu) ? AGG + ((size_t)ra * NREL + ks) * HDIM
                                 : h + (size_t)ea * HDIM;
            pb = (eb == 0xFFFFu) ? nullptr
               : (eb == 0xFFFEu) ? AGG + ((size_t)rb * NREL + ks) * HDIM
                                 : h + (size_t)eb * HDIM;
        }

        bf16x8 a[4][2], b[4][4];
#pragma unroll
        for (int kk = 0; kk < 4; ++kk) {
            int co = kk * 32 + quad * 8;
            a[kk][0] = pa ? *(const bf16x8*)(pa + co) : (bf16x8)0;
            a[kk][1] = pb ? *(const bf16x8*)(pb + co) : (bf16x8)0;
#pragma unroll
            for (int ni = 0; ni < 4; ++ni)
                b[kk][ni] = *(const bf16x8*)(wbase + (size_t)ni * 16 * KDIM + ks * HDIM + co);
        }
#pragma unroll
        for (int kk = 0; kk < 4; ++kk)
#pragma unroll
            for (int mi = 0; mi < 2; ++mi)
#pragma unroll
                for (int ni = 0; ni < 4; ++ni)
                    acc[mi][ni] = __builtin_amdgcn_mfma_f32_16x16x32_bf16(a[kk][mi], b[kk][ni], acc[mi][ni], 0, 0, 0);
    }

    // epilogue: bias + relu, single store.  C/D: col=lane&15, row=quad*4+reg [m89]
#pragma unroll
    for (int mi = 0; mi < 2; ++mi) {
#pragma unroll
        for (int reg = 0; reg < 4; ++reg) {
            int g = row0 + mq + mi * 16 + quad * 4 + reg;
            if (g < rows) {
                size_t gd = (size_t)(c0 + g) * HDIM;
#pragma unroll
                for (int ni = 0; ni < 4; ++ni) {
                    int n = nq + ni * 16 + lr;
                    float v = acc[mi][ni][reg] + bias[n];
                    v = v > 0.f ? v : 0.f;
                    if (out_bf) out_bf[gd + n] = f2bf(v);
                    else        out_f[gd + n] = v;
                }
            }
        }
    }
}

extern "C" void kernel_launch(void* const* d_in, const int* in_sizes, int n_in,
                              void* d_out, int out_size, void* d_ws, size_t ws_size,
                              hipStream_t stream) {
    const float* emb    = (const float*)d_in[0];
    const float* basis1 = (const float*)d_in[1];
    const float* wc1    = (const float*)d_in[2];
    const float* lw1    = (const float*)d_in[3];
    const float* bias1  = (const float*)d_in[4];
    const float* basis2 = (const float*)d_in[5];
    const float* wc2    = (const float*)d_in[6];
    const float* lw2    = (const float*)d_in[7];
    const float* bias2  = (const float*)d_in[8];
    const int* src = (const int*)d_in[9];
    const int* dst = (const int*)d_in[10];
    const int* rel = (const int*)d_in[11];

    int n_ent = in_sizes[0] / HDIM;
    int n_edges = in_sizes[9];
    int NK = n_ent * NREL;
    int NK1 = NK + 1;

    char* ws = (char*)d_ws;
    size_t wo = 0;
    auto alloc = [&](size_t bytes) {
        void* p = ws + wo;
        wo = (wo + bytes + 255) & ~(size_t)255;
        return p;
    };
    int* hist  = (int*)alloc((size_t)NK1 * 4);
    int* off   = (int*)alloc((size_t)NK1 * 4);
    int* cur   = (int*)alloc((size_t)NK * 4);
    int* part  = (int*)alloc(4096);
    int* edge2 = (int*)alloc((size_t)n_edges * 4);
    short* wtL1 = (short*)alloc((size_t)HDIM * KDIM * 2);
    short* wtL2 = (short*)alloc((size_t)HDIM * KDIM * 2);
    short* h0   = (short*)alloc((size_t)n_ent * HDIM * 2);
    short* h1   = (short*)alloc((size_t)n_ent * HDIM * 2);
    unsigned short* srcs = (unsigned short*)alloc((size_t)n_ent * NREL * 2);

    // AGG: single chunk if workspace allows (full = n_ent*4096B = 205MB);
    // shrink to chunked mode otherwise.
    size_t rowBytes = (size_t)NREL * HDIM * 2;   // 4096 B
    size_t avail = (ws_size > wo + rowBytes * 128) ? (ws_size - wo) : rowBytes * 128;
    int CH = (int)(avail / rowBytes);
    if (CH > n_ent) CH = n_ent;
    CH = (CH + 127) & ~127;
    if (CH < 128) CH = 128;
    while ((size_t)CH * rowBytes > avail && CH > 128) CH -= 128;
    short* AGG = (short*)alloc((size_t)CH * rowBytes);

    // weight prep + input cast
    compute_wt<<<NREL * HDIM, HDIM, 0, stream>>>(basis1, wc1, wtL1);
    compute_wt<<<NREL * HDIM, HDIM, 0, stream>>>(basis2, wc2, wtL2);
    transposeL<<<HDIM, HDIM, 0, stream>>>(lw1, wtL1);
    transposeL<<<HDIM, HDIM, 0, stream>>>(lw2, wtL2);
    cast_bf16<<<512, 256, 0, stream>>>(emb, h0, n_ent * HDIM / 4);

    // counting sort by key = dst*16+rel (once; reused by both layers)
    zero_i32<<<(NK1 + 255) / 256, 256, 0, stream>>>(hist, NK1);
    hist_k<<<1024, 256, 0, stream>>>(dst, rel, n_edges, hist);
    int nsb = (NK1 + 1023) / 1024;
    scan_p1<<<nsb, 1024, 0, stream>>>(hist, NK1, off, part);
    scan_p2<<<1, 1024, 0, stream>>>(part, nsb);
    scan_p3<<<nsb, 1024, 0, stream>>>(off, part, NK1, NK, cur);
    scatter_k<<<1024, 256, 0, stream>>>(src, dst, rel, n_edges, cur, edge2);

    // layer 1: h1 = relu([agg|h0] @ Wstack1 + b1)   (bf16 out)
    for (int c0 = 0; c0 < n_ent; c0 += CH) {
        int rows = n_ent - c0 < CH ? n_ent - c0 : CH;
        agg_build<<<(rows * 2 + 15) / 16, 256, 0, stream>>>(h0, off, edge2, AGG, srcs, c0, rows);
        agg_gemm<<<(rows + 63) / 64, 256, 0, stream>>>(AGG, h0, wtL1, srcs, bias1,
                                                       h1, nullptr, c0, rows);
    }
    // layer 2: out = relu([agg|h1] @ Wstack2 + b2)  (fp32 out)
    for (int c0 = 0; c0 < n_ent; c0 += CH) {
        int rows = n_ent - c0 < CH ? n_ent - c0 : CH;
        agg_build<<<(rows * 2 + 15) / 16, 256, 0, stream>>>(h1, off, edge2, AGG, srcs, c0, rows);
        agg_gemm<<<(rows + 63) / 64, 256, 0, stream>>>(AGG, h1, wtL2, srcs, bias2,
                                                       nullptr, (float*)d_out, c0, rows);
    }
}

// Round 8
// 566.334 us; speedup vs baseline: 1.0905x; 1.0905x over previous
//
#include <hip/hip_runtime.h>
#include <hip/hip_bf16.h>

#define HDIM 128
#define NREL 16
#define NBASES 8
#define KSLOTS 17            // 16 relations + self-loop (weights only; AGG stores 16)
#define KDIM (KSLOTS * HDIM) // 2176

typedef short bf16x8 __attribute__((ext_vector_type(8)));
typedef short s16x4 __attribute__((ext_vector_type(4)));
typedef float f32x4 __attribute__((ext_vector_type(4)));

static __device__ __forceinline__ short f2bf(float x) {
    __hip_bfloat16 b = __float2bfloat16(x);
    return *(short*)&b;
}
static __device__ __forceinline__ float bf2f(short u) {
    unsigned v = ((unsigned)(unsigned short)u) << 16;
    return __uint_as_float(v);
}

// async global->LDS DMA, 16B per lane. Global src per-lane; LDS dest is
// wave-uniform base + lane*16 (linear, no LDS write conflicts possible).
static __device__ __forceinline__ void gload_lds16(const void* g, void* l) {
    __builtin_amdgcn_global_load_lds(
        (const __attribute__((address_space(1))) unsigned int*)g,
        (__attribute__((address_space(3))) unsigned int*)l,
        16, 0, 0);
}

// ---------------- weight prep ----------------
// wtL[o][r*128+i] = W_r[i][o] = sum_b wcomp[r][b]*basis[b][i][o]   (bf16)
__global__ void compute_wt(const float* __restrict__ basis,
                           const float* __restrict__ wcomp,
                           short* __restrict__ wtL) {
    int ro = blockIdx.x;
    int r = ro >> 7, o = ro & 127;
    int i = threadIdx.x;
    float acc = 0.f;
#pragma unroll
    for (int b = 0; b < NBASES; ++b)
        acc += wcomp[r * NBASES + b] * basis[(b * HDIM + i) * HDIM + o];
    wtL[(size_t)o * KDIM + r * HDIM + i] = f2bf(acc);
}

// wtL[o][2048+i] = loop_w[i][o]
__global__ void transposeL(const float* __restrict__ in, short* __restrict__ wtL) {
    int o = blockIdx.x, i = threadIdx.x;
    wtL[(size_t)o * KDIM + NREL * HDIM + i] = f2bf(in[i * HDIM + o]);
}

// fp32 -> bf16 cast (vectorized)
__global__ void cast_bf16(const float* __restrict__ in, short* __restrict__ out, int n4) {
    for (int i = blockIdx.x * blockDim.x + threadIdx.x; i < n4; i += gridDim.x * blockDim.x) {
        f32x4 v = ((const f32x4*)in)[i];
        s16x4 o;
#pragma unroll
        for (int j = 0; j < 4; ++j) o[j] = f2bf(v[j]);
        ((s16x4*)out)[i] = o;
    }
}

__global__ void zero_i32(int* __restrict__ p, int n) {
    int i = blockIdx.x * blockDim.x + threadIdx.x;
    if (i < n) p[i] = 0;
}

// ---------------- counting sort by key = dst*16 + rel (800K bins) ----------------
__global__ __launch_bounds__(256) void hist_k(const int* __restrict__ dst,
                                              const int* __restrict__ rel, int n,
                                              int* __restrict__ hist) {
    for (int i = blockIdx.x * blockDim.x + threadIdx.x; i < n; i += gridDim.x * blockDim.x)
        atomicAdd(&hist[dst[i] * NREL + rel[i]], 1);
}

__global__ __launch_bounds__(1024) void scan_p1(const int* __restrict__ hist, int n,
                                                int* __restrict__ off, int* __restrict__ part) {
    __shared__ int sh[1024];
    int t = threadIdx.x, b = blockIdx.x;
    int i = b * 1024 + t;
    int x = (i < n) ? hist[i] : 0;
    sh[t] = x;
    __syncthreads();
    for (int d = 1; d < 1024; d <<= 1) {
        int v = sh[t];
        int u = (t >= d) ? sh[t - d] : 0;
        __syncthreads();
        sh[t] = v + u;
        __syncthreads();
    }
    if (i < n) off[i] = sh[t] - x;
    if (t == 1023) part[b] = sh[t];
}

__global__ __launch_bounds__(1024) void scan_p2(int* __restrict__ part, int nb) {
    __shared__ int sh[1024];
    int t = threadIdx.x;
    int x = (t < nb) ? part[t] : 0;
    sh[t] = x;
    __syncthreads();
    for (int d = 1; d < 1024; d <<= 1) {
        int v = sh[t];
        int u = (t >= d) ? sh[t - d] : 0;
        __syncthreads();
        sh[t] = v + u;
        __syncthreads();
    }
    if (t < nb) part[t] = sh[t] - x;
}

__global__ __launch_bounds__(1024) void scan_p3(int* __restrict__ off, const int* __restrict__ part,
                                                int n, int nk, int* __restrict__ cur) {
    int i = blockIdx.x * 1024 + threadIdx.x;
    if (i < n) {
        int v = off[i] + part[blockIdx.x];
        off[i] = v;
        if (i < nk) cur[i] = v;
    }
}

// place edges: edge2[p] = src | rel<<16  (n_ent < 65536)
__global__ __launch_bounds__(256) void scatter_k(const int* __restrict__ src,
                                                 const int* __restrict__ dst,
                                                 const int* __restrict__ rel, int n,
                                                 int* __restrict__ cur,
                                                 int* __restrict__ edge2) {
    for (int i = blockIdx.x * blockDim.x + threadIdx.x; i < n; i += gridDim.x * blockDim.x) {
        int k = dst[i] * NREL + rel[i];
        int p = atomicAdd(&cur[k], 1);
        edge2[p] = (src[i] & 0xFFFF) | (rel[i] << 16);
    }
}

// ---------------- AGG build: barrier-free streaming gather ----------------
// Group = 16 lanes per (dst row, 8-slot rel-half). Per-slot u16 code:
//   0xFFFF = empty; 0xFFFE = multi (aggregate in AGG); else single src id.
__global__ __launch_bounds__(256) void agg_build(
    const short* __restrict__ h,
    const int* __restrict__ off,      // [NK+1], key-sorted offsets
    const int* __restrict__ edge2,    // src | rel<<16
    short* __restrict__ AGG,          // [rows][16][128] bf16 (valid where srcs==0xFFFE)
    unsigned short* __restrict__ srcs,// [rows][16] slot codes
    int c0, int rows) {
    int tid = threadIdx.x;
    int grp = blockIdx.x * 16 + (tid >> 4);
    int lane16 = tid & 15;
    int lane = tid & 63;
    int gb = lane & 48;               // 16-lane group base within wave
    int drow = grp >> 1;
    if (drow >= rows) return;
    int rh = (grp & 1) * 8;
    int d = c0 + drow;
    int kbase = d * NREL + rh;

    int e0 = off[kbase];
    int e8 = off[kbase + 8];
    int deg = e8 - e0;

    int pkv = (e0 + lane16 < e8) ? edge2[e0 + lane16] : 0;

    int rlv[17], srcv[16];
#pragma unroll
    for (int p = 0; p < 16; ++p) {
        int pk = __shfl(pkv, gb + p);
        rlv[p] = (p < deg) ? (((pk >> 16) & 15) - rh) : 255;
        srcv[p] = pk & 0xFFFF;
    }
    rlv[16] = (deg > 16) ? rlv[15] : 255;

    bool single[16];
#pragma unroll
    for (int p = 0; p < 16; ++p)
        single[p] = ((p == 0) || (rlv[p - 1] != rlv[p])) && (rlv[p + 1] != rlv[p]);

    bf16x8 va[16];
#pragma unroll
    for (int p = 0; p < 16; ++p)
        if (p < deg && !single[p])
            va[p] = *(const bf16x8*)(h + (size_t)srcv[p] * HDIM + lane16 * 8);

    unsigned short val = 0xFFFF;
#pragma unroll
    for (int p = 0; p < 16; ++p)
        if (p < deg && rlv[p] == lane16)
            val = single[p] ? (unsigned short)srcv[p] : (unsigned short)0xFFFE;

    float acc[8] = {0.f, 0.f, 0.f, 0.f, 0.f, 0.f, 0.f, 0.f};
    int cs = -1;
    short* outp = AGG + ((size_t)drow * NREL + rh) * HDIM + lane16 * 8;

    auto emit = [&]() {
        bf16x8 o;
#pragma unroll
        for (int c = 0; c < 8; ++c) o[c] = f2bf(acc[c]);
        *(bf16x8*)(outp + cs * HDIM) = o;
    };
    auto take = [&](int sl, bf16x8 v) {
        if (sl != cs) {
            if (cs >= 0) emit();
            cs = sl;
#pragma unroll
            for (int c = 0; c < 8; ++c) acc[c] = 0.f;
        }
#pragma unroll
        for (int c = 0; c < 8; ++c) acc[c] += bf2f(v[c]);
    };

#pragma unroll
    for (int p = 0; p < 16; ++p)
        if (p < deg && !single[p]) take(rlv[p], va[p]);

    for (int e = e0 + 16; e < e8; ++e) {
        int pk = edge2[e];
        int sl = ((pk >> 16) & 15) - rh;
        if (sl == lane16) val = 0xFFFE;
        bf16x8 v = *(const bf16x8*)(h + (size_t)(pk & 0xFFFF) * HDIM + lane16 * 8);
        take(sl, v);
    }
    if (cs >= 0) emit();

    if (lane16 < 8) srcs[(size_t)drow * NREL + rh + lane16] = val;
}

// ---------------- dense GEMM: out = relu([AGG|h] @ WstackT + bias) ----------------
// Block = 64 rows x 128 cols, 256 threads (4 waves, wave-tile 32x64).
// A staged per slot via global_load_lds DMA: per-lane indirected GLOBAL src
// (zero-row / h[src] / AGG row, via a per-block LDS pointer table), linear
// LDS dest (no write conflicts), inverse-swizzled source chunk + swizzled
// read (rule #21) -> conflict-free ds_read_b128. Double-buffered; one
// barrier per slot (its vmcnt drain lands the prefetch). B read per wave
// straight from L2-hot wtL (no LDS round-trip). 37KB LDS, 3 blocks/CU.
__global__ __launch_bounds__(256, 3) void agg_gemm(
    const char* __restrict__ wsbase,
    unsigned hoff, unsigned aggoff, unsigned zoff,
    const short* __restrict__ wtL,    // [128 o][2176 k] bf16
    const unsigned short* __restrict__ srcs, // [rows][16]
    const float* __restrict__ bias,   // [128]
    short* __restrict__ out_bf,       // layer-1 output (bf16) or nullptr
    float* __restrict__ out_f,        // layer-2 output (fp32) or nullptr
    int c0, int rows) {
    __shared__ short A0[64 * HDIM];   // 16 KB
    __shared__ short A1[64 * HDIM];   // 16 KB
    __shared__ unsigned ptab[64 * KSLOTS]; // 4.25 KB row-source offsets

    int tid = threadIdx.x;
    int row0 = blockIdx.x * 64;
    int wave = tid >> 6, lane = tid & 63;
    int mq = (wave & 1) * 32, nq = (wave >> 1) * 64;
    int lr = lane & 15, quad = lane >> 4;

    // ---- build pointer table: one u32 ws-offset per (row, slot) ----
    if (tid < 64) {
        int r = tid;
        int gr = row0 + r;             // chunk-local row
        bool v = gr < rows;
        const unsigned short* sc = srcs + (size_t)gr * NREL;
#pragma unroll
        for (int ks = 0; ks < NREL; ++ks) {
            unsigned e = v ? (unsigned)sc[ks] : 0xFFFFu;
            unsigned o = (e == 0xFFFFu) ? zoff
                       : (e == 0xFFFEu) ? aggoff + (unsigned)(((size_t)gr * NREL + ks) << 8)
                                        : hoff + (e << 8);
            ptab[r * KSLOTS + ks] = o;
        }
        ptab[r * KSLOTS + 16] = v ? hoff + ((unsigned)(c0 + gr) << 8) : zoff;
    }
    __syncthreads();

    // ---- staging: 16 wave-issues x 1KB DMA; src chunk inverse-swizzled ----
    auto stage = [&](int ks, short* buf) {
#pragma unroll
        for (int i = 0; i < 4; ++i) {
            int r = (wave * 4 + i) * 4 + (lane >> 4);
            unsigned o = ptab[r * KSLOTS + ks];
            unsigned csrc = (unsigned)(((lane & 15) ^ (r & 7)) * 16);
            gload_lds16(wsbase + o + csrc, buf + (wave * 4 + i) * 512);
        }
    };

    f32x4 acc[2][4] = {};
    const short* wb = wtL + (size_t)(nq + lr) * KDIM;

    stage(0, A0);
    __syncthreads();

#pragma unroll 1
    for (int ks = 0; ks < KSLOTS; ++ks) {
        const short* Ab = (ks & 1) ? A1 : A0;
        if (ks + 1 < KSLOTS) stage(ks + 1, (ks & 1) ? A0 : A1);
#pragma unroll
        for (int kk = 0; kk < 4; ++kk) {
            bf16x8 b4[4];
#pragma unroll
            for (int ni = 0; ni < 4; ++ni)
                b4[ni] = *(const bf16x8*)(wb + (size_t)ni * 16 * KDIM + ks * HDIM + kk * 32 + quad * 8);
            bf16x8 a2[2];
#pragma unroll
            for (int mi = 0; mi < 2; ++mi) {
                int r = mq + mi * 16 + lr;
                int ch = (kk * 4 + quad) ^ (r & 7);   // swizzled read (matches src swz)
                a2[mi] = *(const bf16x8*)(Ab + r * HDIM + ch * 8);
            }
#pragma unroll
            for (int mi = 0; mi < 2; ++mi)
#pragma unroll
                for (int ni = 0; ni < 4; ++ni)
                    acc[mi][ni] = __builtin_amdgcn_mfma_f32_16x16x32_bf16(a2[mi], b4[ni], acc[mi][ni], 0, 0, 0);
        }
        __syncthreads();   // LDS reads done + vmcnt drained (next buf ready)
    }

    // epilogue: bias + relu, single store.  C/D: col=lane&15, row=quad*4+reg [m89]
#pragma unroll
    for (int mi = 0; mi < 2; ++mi) {
#pragma unroll
        for (int reg = 0; reg < 4; ++reg) {
            int g = row0 + mq + mi * 16 + quad * 4 + reg;
            if (g < rows) {
                size_t gd = (size_t)(c0 + g) * HDIM;
#pragma unroll
                for (int ni = 0; ni < 4; ++ni) {
                    int n = nq + ni * 16 + lr;
                    float v = acc[mi][ni][reg] + bias[n];
                    v = v > 0.f ? v : 0.f;
                    if (out_bf) out_bf[gd + n] = f2bf(v);
                    else        out_f[gd + n] = v;
                }
            }
        }
    }
}

extern "C" void kernel_launch(void* const* d_in, const int* in_sizes, int n_in,
                              void* d_out, int out_size, void* d_ws, size_t ws_size,
                              hipStream_t stream) {
    const float* emb    = (const float*)d_in[0];
    const float* basis1 = (const float*)d_in[1];
    const float* wc1    = (const float*)d_in[2];
    const float* lw1    = (const float*)d_in[3];
    const float* bias1  = (const float*)d_in[4];
    const float* basis2 = (const float*)d_in[5];
    const float* wc2    = (const float*)d_in[6];
    const float* lw2    = (const float*)d_in[7];
    const float* bias2  = (const float*)d_in[8];
    const int* src = (const int*)d_in[9];
    const int* dst = (const int*)d_in[10];
    const int* rel = (const int*)d_in[11];

    int n_ent = in_sizes[0] / HDIM;
    int n_edges = in_sizes[9];
    int NK = n_ent * NREL;
    int NK1 = NK + 1;

    char* ws = (char*)d_ws;
    size_t wo = 0;
    auto alloc = [&](size_t bytes) {
        void* p = ws + wo;
        wo = (wo + bytes + 255) & ~(size_t)255;
        return p;
    };
    int* hist  = (int*)alloc((size_t)NK1 * 4);
    int* off   = (int*)alloc((size_t)NK1 * 4);
    int* cur   = (int*)alloc((size_t)NK * 4);
    int* part  = (int*)alloc(4096);
    int* edge2 = (int*)alloc((size_t)n_edges * 4);
    short* wtL1 = (short*)alloc((size_t)HDIM * KDIM * 2);
    short* wtL2 = (short*)alloc((size_t)HDIM * KDIM * 2);
    short* h0   = (short*)alloc((size_t)n_ent * HDIM * 2);
    short* h1   = (short*)alloc((size_t)n_ent * HDIM * 2);
    unsigned short* srcs = (unsigned short*)alloc((size_t)n_ent * NREL * 2);
    int* zrow   = (int*)alloc(256);               // 256B zero row for empty slots

    // AGG: single chunk if workspace allows (full = n_ent*4096B = 205MB)
    size_t rowBytes = (size_t)NREL * HDIM * 2;   // 4096 B
    size_t avail = (ws_size > wo + rowBytes * 128) ? (ws_size - wo) : rowBytes * 128;
    int CH = (int)(avail / rowBytes);
    if (CH > n_ent) CH = n_ent;
    CH = (CH + 127) & ~127;
    if (CH < 128) CH = 128;
    while ((size_t)CH * rowBytes > avail && CH > 128) CH -= 128;
    short* AGG = (short*)alloc((size_t)CH * rowBytes);

    unsigned h0off  = (unsigned)((char*)h0 - ws);
    unsigned h1off  = (unsigned)((char*)h1 - ws);
    unsigned aggoff = (unsigned)((char*)AGG - ws);
    unsigned zoff   = (unsigned)((char*)zrow - ws);

    // weight prep + input cast
    compute_wt<<<NREL * HDIM, HDIM, 0, stream>>>(basis1, wc1, wtL1);
    compute_wt<<<NREL * HDIM, HDIM, 0, stream>>>(basis2, wc2, wtL2);
    transposeL<<<HDIM, HDIM, 0, stream>>>(lw1, wtL1);
    transposeL<<<HDIM, HDIM, 0, stream>>>(lw2, wtL2);
    cast_bf16<<<512, 256, 0, stream>>>(emb, h0, n_ent * HDIM / 4);
    zero_i32<<<1, 64, 0, stream>>>(zrow, 64);

    // counting sort by key = dst*16+rel (once; reused by both layers)
    zero_i32<<<(NK1 + 255) / 256, 256, 0, stream>>>(hist, NK1);
    hist_k<<<1024, 256, 0, stream>>>(dst, rel, n_edges, hist);
    int nsb = (NK1 + 1023) / 1024;
    scan_p1<<<nsb, 1024, 0, stream>>>(hist, NK1, off, part);
    scan_p2<<<1, 1024, 0, stream>>>(part, nsb);
    scan_p3<<<nsb, 1024, 0, stream>>>(off, part, NK1, NK, cur);
    scatter_k<<<1024, 256, 0, stream>>>(src, dst, rel, n_edges, cur, edge2);

    // layer 1: h1 = relu([agg|h0] @ Wstack1 + b1)   (bf16 out)
    for (int c0 = 0; c0 < n_ent; c0 += CH) {
        int rows = n_ent - c0 < CH ? n_ent - c0 : CH;
        agg_build<<<(rows * 2 + 15) / 16, 256, 0, stream>>>(h0, off, edge2, AGG, srcs, c0, rows);
        agg_gemm<<<(rows + 63) / 64, 256, 0, stream>>>(ws, h0off, aggoff, zoff, wtL1, srcs,
                                                       bias1, h1, nullptr, c0, rows);
    }
    // layer 2: out = relu([agg|h1] @ Wstack2 + b2)  (fp32 out)
    for (int c0 = 0; c0 < n_ent; c0 += CH) {
        int rows = n_ent - c0 < CH ? n_ent - c0 : CH;
        agg_build<<<(rows * 2 + 15) / 16, 256, 0, stream>>>(h1, off, edge2, AGG, srcs, c0, rows);
        agg_gemm<<<(rows + 63) / 64, 256, 0, stream>>>(ws, h1off, aggoff, zoff, wtL2, srcs,
                                                       bias2, nullptr, (float*)d_out, c0, rows);
    }
}

// Round 9
// 533.909 us; speedup vs baseline: 1.1567x; 1.0607x over previous
//
#include <hip/hip_runtime.h>
#include <hip/hip_bf16.h>

#define HDIM 128
#define NREL 16
#define NBASES 8
#define KSLOTS 17            // 16 relations + self-loop (weights only; AGG stores 16)
#define KDIM (KSLOTS * HDIM) // 2176

typedef short bf16x8 __attribute__((ext_vector_type(8)));
typedef short s16x4 __attribute__((ext_vector_type(4)));
typedef float f32x4 __attribute__((ext_vector_type(4)));

static __device__ __forceinline__ short f2bf(float x) {
    __hip_bfloat16 b = __float2bfloat16(x);
    return *(short*)&b;
}
static __device__ __forceinline__ float bf2f(short u) {
    unsigned v = ((unsigned)(unsigned short)u) << 16;
    return __uint_as_float(v);
}

// async global->LDS DMA, 16B per lane. Global src per-lane; LDS dest is
// wave-uniform base + lane*16 (linear, no LDS write conflicts possible).
static __device__ __forceinline__ void gload_lds16(const void* g, void* l) {
    __builtin_amdgcn_global_load_lds(
        (const __attribute__((address_space(1))) unsigned int*)g,
        (__attribute__((address_space(3))) unsigned int*)l,
        16, 0, 0);
}

// ---------------- weight prep ----------------
// wtL[o][r*128+i] = W_r[i][o] = sum_b wcomp[r][b]*basis[b][i][o]   (bf16)
__global__ void compute_wt(const float* __restrict__ basis,
                           const float* __restrict__ wcomp,
                           short* __restrict__ wtL) {
    int ro = blockIdx.x;
    int r = ro >> 7, o = ro & 127;
    int i = threadIdx.x;
    float acc = 0.f;
#pragma unroll
    for (int b = 0; b < NBASES; ++b)
        acc += wcomp[r * NBASES + b] * basis[(b * HDIM + i) * HDIM + o];
    wtL[(size_t)o * KDIM + r * HDIM + i] = f2bf(acc);
}

// wtL[o][2048+i] = loop_w[i][o]
__global__ void transposeL(const float* __restrict__ in, short* __restrict__ wtL) {
    int o = blockIdx.x, i = threadIdx.x;
    wtL[(size_t)o * KDIM + NREL * HDIM + i] = f2bf(in[i * HDIM + o]);
}

// fp32 -> bf16 cast (vectorized)
__global__ void cast_bf16(const float* __restrict__ in, short* __restrict__ out, int n4) {
    for (int i = blockIdx.x * blockDim.x + threadIdx.x; i < n4; i += gridDim.x * blockDim.x) {
        f32x4 v = ((const f32x4*)in)[i];
        s16x4 o;
#pragma unroll
        for (int j = 0; j < 4; ++j) o[j] = f2bf(v[j]);
        ((s16x4*)out)[i] = o;
    }
}

__global__ void zero_i32(int* __restrict__ p, int n) {
    int i = blockIdx.x * blockDim.x + threadIdx.x;
    if (i < n) p[i] = 0;
}

// ---------------- counting sort by key = dst*16 + rel (800K bins) ----------------
__global__ __launch_bounds__(256) void hist_k(const int* __restrict__ dst,
                                              const int* __restrict__ rel, int n,
                                              int* __restrict__ hist) {
    for (int i = blockIdx.x * blockDim.x + threadIdx.x; i < n; i += gridDim.x * blockDim.x)
        atomicAdd(&hist[dst[i] * NREL + rel[i]], 1);
}

__global__ __launch_bounds__(1024) void scan_p1(const int* __restrict__ hist, int n,
                                                int* __restrict__ off, int* __restrict__ part) {
    __shared__ int sh[1024];
    int t = threadIdx.x, b = blockIdx.x;
    int i = b * 1024 + t;
    int x = (i < n) ? hist[i] : 0;
    sh[t] = x;
    __syncthreads();
    for (int d = 1; d < 1024; d <<= 1) {
        int v = sh[t];
        int u = (t >= d) ? sh[t - d] : 0;
        __syncthreads();
        sh[t] = v + u;
        __syncthreads();
    }
    if (i < n) off[i] = sh[t] - x;
    if (t == 1023) part[b] = sh[t];
}

__global__ __launch_bounds__(1024) void scan_p2(int* __restrict__ part, int nb) {
    __shared__ int sh[1024];
    int t = threadIdx.x;
    int x = (t < nb) ? part[t] : 0;
    sh[t] = x;
    __syncthreads();
    for (int d = 1; d < 1024; d <<= 1) {
        int v = sh[t];
        int u = (t >= d) ? sh[t - d] : 0;
        __syncthreads();
        sh[t] = v + u;
        __syncthreads();
    }
    if (t < nb) part[t] = sh[t] - x;
}

__global__ __launch_bounds__(1024) void scan_p3(int* __restrict__ off, const int* __restrict__ part,
                                                int n, int nk, int* __restrict__ cur) {
    int i = blockIdx.x * 1024 + threadIdx.x;
    if (i < n) {
        int v = off[i] + part[blockIdx.x];
        off[i] = v;
        if (i < nk) cur[i] = v;
    }
}

// place edges: edge2[p] = src | rel<<16  (n_ent < 65536)
__global__ __launch_bounds__(256) void scatter_k(const int* __restrict__ src,
                                                 const int* __restrict__ dst,
                                                 const int* __restrict__ rel, int n,
                                                 int* __restrict__ cur,
                                                 int* __restrict__ edge2) {
    for (int i = blockIdx.x * blockDim.x + threadIdx.x; i < n; i += gridDim.x * blockDim.x) {
        int k = dst[i] * NREL + rel[i];
        int p = atomicAdd(&cur[k], 1);
        edge2[p] = (src[i] & 0xFFFF) | (rel[i] << 16);
    }
}

// ---------------- AGG build: barrier-free streaming gather ----------------
// Group = 16 lanes per (dst row, 8-slot rel-half). Per-slot u16 code:
//   0xFFFF = empty; 0xFFFE = multi (aggregate in AGG); else single src id.
__global__ __launch_bounds__(256) void agg_build(
    const short* __restrict__ h,
    const int* __restrict__ off,      // [NK+1], key-sorted offsets
    const int* __restrict__ edge2,    // src | rel<<16
    short* __restrict__ AGG,          // [rows][16][128] bf16 (valid where srcs==0xFFFE)
    unsigned short* __restrict__ srcs,// [rows][16] slot codes
    int c0, int rows) {
    int tid = threadIdx.x;
    int grp = blockIdx.x * 16 + (tid >> 4);
    int lane16 = tid & 15;
    int lane = tid & 63;
    int gb = lane & 48;               // 16-lane group base within wave
    int drow = grp >> 1;
    if (drow >= rows) return;
    int rh = (grp & 1) * 8;
    int d = c0 + drow;
    int kbase = d * NREL + rh;

    int e0 = off[kbase];
    int e8 = off[kbase + 8];
    int deg = e8 - e0;

    int pkv = (e0 + lane16 < e8) ? edge2[e0 + lane16] : 0;

    int rlv[17], srcv[16];
#pragma unroll
    for (int p = 0; p < 16; ++p) {
        int pk = __shfl(pkv, gb + p);
        rlv[p] = (p < deg) ? (((pk >> 16) & 15) - rh) : 255;
        srcv[p] = pk & 0xFFFF;
    }
    rlv[16] = (deg > 16) ? rlv[15] : 255;

    bool single[16];
#pragma unroll
    for (int p = 0; p < 16; ++p)
        single[p] = ((p == 0) || (rlv[p - 1] != rlv[p])) && (rlv[p + 1] != rlv[p]);

    bf16x8 va[16];
#pragma unroll
    for (int p = 0; p < 16; ++p)
        if (p < deg && !single[p])
            va[p] = *(const bf16x8*)(h + (size_t)srcv[p] * HDIM + lane16 * 8);

    unsigned short val = 0xFFFF;
#pragma unroll
    for (int p = 0; p < 16; ++p)
        if (p < deg && rlv[p] == lane16)
            val = single[p] ? (unsigned short)srcv[p] : (unsigned short)0xFFFE;

    float acc[8] = {0.f, 0.f, 0.f, 0.f, 0.f, 0.f, 0.f, 0.f};
    int cs = -1;
    short* outp = AGG + ((size_t)drow * NREL + rh) * HDIM + lane16 * 8;

    auto emit = [&]() {
        bf16x8 o;
#pragma unroll
        for (int c = 0; c < 8; ++c) o[c] = f2bf(acc[c]);
        *(bf16x8*)(outp + cs * HDIM) = o;
    };
    auto take = [&](int sl, bf16x8 v) {
        if (sl != cs) {
            if (cs >= 0) emit();
            cs = sl;
#pragma unroll
            for (int c = 0; c < 8; ++c) acc[c] = 0.f;
        }
#pragma unroll
        for (int c = 0; c < 8; ++c) acc[c] += bf2f(v[c]);
    };

#pragma unroll
    for (int p = 0; p < 16; ++p)
        if (p < deg && !single[p]) take(rlv[p], va[p]);

    for (int e = e0 + 16; e < e8; ++e) {
        int pk = edge2[e];
        int sl = ((pk >> 16) & 15) - rh;
        if (sl == lane16) val = 0xFFFE;
        bf16x8 v = *(const bf16x8*)(h + (size_t)(pk & 0xFFFF) * HDIM + lane16 * 8);
        take(sl, v);
    }
    if (cs >= 0) emit();

    if (lane16 < 8) srcs[(size_t)drow * NREL + rh + lane16] = val;
}

// ---------------- dense GEMM: out = relu([AGG|h] @ WstackT + bias) ----------------
// Block = 32 rows x 128 cols, 128 threads (2 waves, wave-tile 32x64).
// Small blocks = small barrier scope: only 2 waves couple at each slot
// barrier, and ~8 independent blocks/CU (16 waves) interleave so one
// block's DMA-drain stall hides under other blocks' MFMAs. A staged per
// slot via global_load_lds DMA (per-lane indirected global src from a
// per-block pointer table; linear LDS dest; inverse-swizzled source chunk
// + swizzled read, rule #21). Double-buffered; one barrier per slot.
// B read per wave straight from L2-hot wtL. ~18.5KB LDS.
__global__ __launch_bounds__(128, 4) void agg_gemm(
    const char* __restrict__ wsbase,
    unsigned hoff, unsigned aggoff, unsigned zoff,
    const short* __restrict__ wtL,    // [128 o][2176 k] bf16
    const unsigned short* __restrict__ srcs, // [rows][16]
    const float* __restrict__ bias,   // [128]
    short* __restrict__ out_bf,       // layer-1 output (bf16) or nullptr
    float* __restrict__ out_f,        // layer-2 output (fp32) or nullptr
    int c0, int rows) {
    __shared__ short A0[32 * HDIM];   // 8 KB
    __shared__ short A1[32 * HDIM];   // 8 KB
    __shared__ unsigned ptab[32 * KSLOTS]; // 2.2 KB row-source offsets

    int tid = threadIdx.x;
    int row0 = blockIdx.x * 32;
    int wave = tid >> 6, lane = tid & 63;
    int nq = wave * 64;               // wave owns cols [nq, nq+64)
    int lr = lane & 15, quad = lane >> 4;

    // ---- build pointer table: one u32 ws-offset per (row, slot) ----
    if (tid < 32) {
        int r = tid;
        int gr = row0 + r;             // chunk-local row
        bool v = gr < rows;
        const unsigned short* sc = srcs + (size_t)gr * NREL;
#pragma unroll
        for (int ks = 0; ks < NREL; ++ks) {
            unsigned e = v ? (unsigned)sc[ks] : 0xFFFFu;
            unsigned o = (e == 0xFFFFu) ? zoff
                       : (e == 0xFFFEu) ? aggoff + (unsigned)(((size_t)gr * NREL + ks) << 8)
                                        : hoff + (e << 8);
            ptab[r * KSLOTS + ks] = o;
        }
        ptab[r * KSLOTS + 16] = v ? hoff + ((unsigned)(c0 + gr) << 8) : zoff;
    }
    __syncthreads();

    // ---- staging: 8 wave-issues x 1KB DMA; src chunk inverse-swizzled ----
    auto stage = [&](int ks, short* buf) {
#pragma unroll
        for (int i = 0; i < 4; ++i) {
            int r = (wave * 4 + i) * 4 + (lane >> 4);
            unsigned o = ptab[r * KSLOTS + ks];
            unsigned csrc = (unsigned)(((lane & 15) ^ (r & 7)) * 16);
            gload_lds16(wsbase + o + csrc, buf + (wave * 4 + i) * 512);
        }
    };

    f32x4 acc[2][4] = {};
    const short* wb = wtL + (size_t)(nq + lr) * KDIM;

    stage(0, A0);
    __syncthreads();

#pragma unroll 1
    for (int ks = 0; ks < KSLOTS; ++ks) {
        const short* Ab = (ks & 1) ? A1 : A0;
        if (ks + 1 < KSLOTS) stage(ks + 1, (ks & 1) ? A0 : A1);
#pragma unroll
        for (int kk = 0; kk < 4; ++kk) {
            bf16x8 b4[4];
#pragma unroll
            for (int ni = 0; ni < 4; ++ni)
                b4[ni] = *(const bf16x8*)(wb + (size_t)ni * 16 * KDIM + ks * HDIM + kk * 32 + quad * 8);
            bf16x8 a2[2];
#pragma unroll
            for (int mi = 0; mi < 2; ++mi) {
                int r = mi * 16 + lr;
                int ch = (kk * 4 + quad) ^ (r & 7);   // swizzled read (matches src swz)
                a2[mi] = *(const bf16x8*)(Ab + r * HDIM + ch * 8);
            }
#pragma unroll
            for (int mi = 0; mi < 2; ++mi)
#pragma unroll
                for (int ni = 0; ni < 4; ++ni)
                    acc[mi][ni] = __builtin_amdgcn_mfma_f32_16x16x32_bf16(a2[mi], b4[ni], acc[mi][ni], 0, 0, 0);
        }
        __syncthreads();   // LDS reads done + vmcnt drained (next buf ready)
    }

    // epilogue: bias + relu, single store.  C/D: col=lane&15, row=quad*4+reg [m89]
#pragma unroll
    for (int mi = 0; mi < 2; ++mi) {
#pragma unroll
        for (int reg = 0; reg < 4; ++reg) {
            int g = row0 + mi * 16 + quad * 4 + reg;
            if (g < rows) {
                size_t gd = (size_t)(c0 + g) * HDIM;
#pragma unroll
                for (int ni = 0; ni < 4; ++ni) {
                    int n = nq + ni * 16 + lr;
                    float v = acc[mi][ni][reg] + bias[n];
                    v = v > 0.f ? v : 0.f;
                    if (out_bf) out_bf[gd + n] = f2bf(v);
                    else        out_f[gd + n] = v;
                }
            }
        }
    }
}

extern "C" void kernel_launch(void* const* d_in, const int* in_sizes, int n_in,
                              void* d_out, int out_size, void* d_ws, size_t ws_size,
                              hipStream_t stream) {
    const float* emb    = (const float*)d_in[0];
    const float* basis1 = (const float*)d_in[1];
    const float* wc1    = (const float*)d_in[2];
    const float* lw1    = (const float*)d_in[3];
    const float* bias1  = (const float*)d_in[4];
    const float* basis2 = (const float*)d_in[5];
    const float* wc2    = (const float*)d_in[6];
    const float* lw2    = (const float*)d_in[7];
    const float* bias2  = (const float*)d_in[8];
    const int* src = (const int*)d_in[9];
    const int* dst = (const int*)d_in[10];
    const int* rel = (const int*)d_in[11];

    int n_ent = in_sizes[0] / HDIM;
    int n_edges = in_sizes[9];
    int NK = n_ent * NREL;
    int NK1 = NK + 1;

    char* ws = (char*)d_ws;
    size_t wo = 0;
    auto alloc = [&](size_t bytes) {
        void* p = ws + wo;
        wo = (wo + bytes + 255) & ~(size_t)255;
        return p;
    };
    int* hist  = (int*)alloc((size_t)NK1 * 4);
    int* off   = (int*)alloc((size_t)NK1 * 4);
    int* cur   = (int*)alloc((size_t)NK * 4);
    int* part  = (int*)alloc(4096);
    int* edge2 = (int*)alloc((size_t)n_edges * 4);
    short* wtL1 = (short*)alloc((size_t)HDIM * KDIM * 2);
    short* wtL2 = (short*)alloc((size_t)HDIM * KDIM * 2);
    short* h0   = (short*)alloc((size_t)n_ent * HDIM * 2);
    short* h1   = (short*)alloc((size_t)n_ent * HDIM * 2);
    unsigned short* srcs = (unsigned short*)alloc((size_t)n_ent * NREL * 2);
    int* zrow   = (int*)alloc(256);               // 256B zero row for empty slots

    // AGG: single chunk if workspace allows (full = n_ent*4096B = 205MB)
    size_t rowBytes = (size_t)NREL * HDIM * 2;   // 4096 B
    size_t avail = (ws_size > wo + rowBytes * 128) ? (ws_size - wo) : rowBytes * 128;
    int CH = (int)(avail / rowBytes);
    if (CH > n_ent) CH = n_ent;
    CH = (CH + 127) & ~127;
    if (CH < 128) CH = 128;
    while ((size_t)CH * rowBytes > avail && CH > 128) CH -= 128;
    short* AGG = (short*)alloc((size_t)CH * rowBytes);

    unsigned h0off  = (unsigned)((char*)h0 - ws);
    unsigned h1off  = (unsigned)((char*)h1 - ws);
    unsigned aggoff = (unsigned)((char*)AGG - ws);
    unsigned zoff   = (unsigned)((char*)zrow - ws);

    // weight prep + input cast
    compute_wt<<<NREL * HDIM, HDIM, 0, stream>>>(basis1, wc1, wtL1);
    compute_wt<<<NREL * HDIM, HDIM, 0, stream>>>(basis2, wc2, wtL2);
    transposeL<<<HDIM, HDIM, 0, stream>>>(lw1, wtL1);
    transposeL<<<HDIM, HDIM, 0, stream>>>(lw2, wtL2);
    cast_bf16<<<512, 256, 0, stream>>>(emb, h0, n_ent * HDIM / 4);
    zero_i32<<<1, 64, 0, stream>>>(zrow, 64);

    // counting sort by key = dst*16+rel (once; reused by both layers)
    zero_i32<<<(NK1 + 255) / 256, 256, 0, stream>>>(hist, NK1);
    hist_k<<<1024, 256, 0, stream>>>(dst, rel, n_edges, hist);
    int nsb = (NK1 + 1023) / 1024;
    scan_p1<<<nsb, 1024, 0, stream>>>(hist, NK1, off, part);
    scan_p2<<<1, 1024, 0, stream>>>(part, nsb);
    scan_p3<<<nsb, 1024, 0, stream>>>(off, part, NK1, NK, cur);
    scatter_k<<<1024, 256, 0, stream>>>(src, dst, rel, n_edges, cur, edge2);

    // layer 1: h1 = relu([agg|h0] @ Wstack1 + b1)   (bf16 out)
    for (int c0 = 0; c0 < n_ent; c0 += CH) {
        int rows = n_ent - c0 < CH ? n_ent - c0 : CH;
        agg_build<<<(rows * 2 + 15) / 16, 256, 0, stream>>>(h0, off, edge2, AGG, srcs, c0, rows);
        agg_gemm<<<(rows + 31) / 32, 128, 0, stream>>>(ws, h0off, aggoff, zoff, wtL1, srcs,
                                                       bias1, h1, nullptr, c0, rows);
    }
    // layer 2: out = relu([agg|h1] @ Wstack2 + b2)  (fp32 out)
    for (int c0 = 0; c0 < n_ent; c0 += CH) {
        int rows = n_ent - c0 < CH ? n_ent - c0 : CH;
        agg_build<<<(rows * 2 + 15) / 16, 256, 0, stream>>>(h1, off, edge2, AGG, srcs, c0, rows);
        agg_gemm<<<(rows + 31) / 32, 128, 0, stream>>>(ws, h1off, aggoff, zoff, wtL2, srcs,
                                                       bias2, nullptr, (float*)d_out, c0, rows);
    }
}